// Round 4
// baseline (747.069 us; speedup 1.0000x reference)
//
#include <hip/hip_runtime.h>
#include <stdint.h>

// Problem constants (match reference)
#define USER_N 100000
#define ITEM_N 50000
#define TAG_N  20000
#define NN (USER_N + ITEM_N)   // 150000 interaction-graph nodes
#define MM (ITEM_N + TAG_N)    // 70000 tag-graph nodes
#define DD 64

// Bucket scatter geometry (R12)
#define BSH 9
#define BROWS (1 << BSH)       // 512 rows per bucket
#define MAXBKT 293             // ceil(NN/512) — largest graph
#define BCAP 16                // LDS staged records per bucket
#define BIN_BLOCKS 64
#define BIN_THREADS 1024

// ---------------------------------------------------------------------------
// JAX threefry2x32 (20 rounds), bit-exact (verified: R1 absmax 0.0).
// ---------------------------------------------------------------------------
__host__ __device__ __forceinline__ void tf2x32(uint32_t k0, uint32_t k1,
                                                uint32_t x0, uint32_t x1,
                                                uint32_t* o0, uint32_t* o1) {
  uint32_t ks2 = k0 ^ k1 ^ 0x1BD11BDAu;
#define ROTL32(v, d) (((v) << (d)) | ((v) >> (32 - (d))))
#define TF_RND(d) { x0 += x1; x1 = ROTL32(x1, d); x1 ^= x0; }
  x0 += k0; x1 += k1;
  TF_RND(13) TF_RND(15) TF_RND(26) TF_RND(6)
  x0 += k1;  x1 += ks2 + 1u;
  TF_RND(17) TF_RND(29) TF_RND(16) TF_RND(24)
  x0 += ks2; x1 += k0 + 2u;
  TF_RND(13) TF_RND(15) TF_RND(26) TF_RND(6)
  x0 += k0;  x1 += k1 + 3u;
  TF_RND(17) TF_RND(29) TF_RND(16) TF_RND(24)
  x0 += k1;  x1 += ks2 + 4u;
  TF_RND(13) TF_RND(15) TF_RND(26) TF_RND(6)
  x0 += ks2; x1 += k0 + 5u;
  *o0 = x0; *o1 = x1;
#undef TF_RND
#undef ROTL32
}

// keep-mask(e; key), bit-exact vs jax uniform+floor
__device__ __forceinline__ float drop_mask(uint32_t e, uint32_t k0, uint32_t k1) {
  uint32_t o0, o1;
  tf2x32(k0, k1, 0u, e, &o0, &o1);
  uint32_t bits = o0 ^ o1;
  float u = __uint_as_float((bits >> 9) | 0x3F800000u) - 1.0f;
  return floorf(u + 0.9f);
}

// bf16 helpers: RNE pack, exact shl unpack
__device__ __forceinline__ uint32_t f2bf(float f) {
  uint32_t u = __float_as_uint(f);
  return (u + 0x7fffu + ((u >> 16) & 1u)) >> 16;
}
__device__ __forceinline__ float bflo(uint32_t u) { return __uint_as_float(u << 16); }
__device__ __forceinline__ float bfhi(uint32_t u) { return __uint_as_float(u & 0xffff0000u); }

// ---------------------------------------------------------------------------
// CSR build (R12): histpack -> scan -> BUCKET BIN (full-line appends) ->
// LOCAL SORT (per-bucket block, LDS row cursors).
// R11 post-mortem: scatter_part WRITE 108 MB for 16 MB rec (partial-line
// writeback persists even with XCD partitioning: a line's 8 records arrive
// over the WHOLE kernel lifetime -> dirty line evicted partially between
// writes) and FETCH 98 MB (NT loads bypass L3 -> the x8 partition re-read
// hit HBM). Correct invariant: a line must be fully written within ONE
// block's short lifetime. bin: stream edges once, stage per-bucket (512-row
// ranges) in LDS, flush ALIGNED 64 B 8-record groups via per-bucket global
// cursor (bucket stage bases 8-aligned by construction; rare overflow
// fallback appends singly). localsort: one block per bucket reads its ~55 KB
// stage region sequentially, places records at final CSR offsets via LDS
// row cursors -> random writes confined to a 55 KB region written by one
// block in ~us -> lines coalesce in that XCD's L2 before writeback.
// Staged record: {col | rowlo<<18, pk} (18+9+32 bits); final: {col*DD, pk}.
// ---------------------------------------------------------------------------

// Coalesced pass: histogram atomic + threefry drop masks for BOTH layers,
// packed 2x bf16 into pk[e] (full lane utilization; pk write is coalesced).
__global__ void histpack_kernel(const int* __restrict__ rows, const float* __restrict__ vals,
                                int* __restrict__ cnt, uint32_t* __restrict__ pk, int nE,
                                uint32_t ka0, uint32_t ka1, uint32_t kb0, uint32_t kb1) {
  int e = blockIdx.x * blockDim.x + threadIdx.x;
  if (e >= nE) return;
  atomicAdd(&cnt[rows[e]], 1);
  const float SC = (float)(1.0 / 0.9);
  float v  = vals[e];
  float v0 = v * drop_mask((uint32_t)e, ka0, ka1) * SC;
  float v1 = v * drop_mask((uint32_t)e, kb0, kb1) * SC;
  pk[e] = f2bf(v0) | (f2bf(v1) << 16);   // dropped -> exact 0 bits
}

__global__ void scan1_kernel(const int* __restrict__ cnt, int* __restrict__ rp,
                             int* __restrict__ bsum, int n) {
  __shared__ int s[256];
  int t = threadIdx.x;
  int base = blockIdx.x * 1024 + t * 4;
  int c0 = (base + 0 < n) ? cnt[base + 0] : 0;
  int c1 = (base + 1 < n) ? cnt[base + 1] : 0;
  int c2 = (base + 2 < n) ? cnt[base + 2] : 0;
  int c3 = (base + 3 < n) ? cnt[base + 3] : 0;
  int tsum = c0 + c1 + c2 + c3;
  s[t] = tsum;
  __syncthreads();
  for (int off = 1; off < 256; off <<= 1) {
    int v = (t >= off) ? s[t - off] : 0;
    __syncthreads();
    s[t] += v;
    __syncthreads();
  }
  int excl = s[t] - tsum;
  if (base + 0 < n) rp[base + 0] = excl;
  if (base + 1 < n) rp[base + 1] = excl + c0;
  if (base + 2 < n) rp[base + 2] = excl + c0 + c1;
  if (base + 3 < n) rp[base + 3] = excl + c0 + c1 + c2;
  if (t == 255) bsum[blockIdx.x] = s[255];
}

__global__ void scan2_kernel(int* __restrict__ bsum, int B) {
  __shared__ int s[256];
  int t = threadIdx.x;
  int v = (t < B) ? bsum[t] : 0;
  s[t] = v;
  __syncthreads();
  for (int off = 1; off < 256; off <<= 1) {
    int x = (t >= off) ? s[t - off] : 0;
    __syncthreads();
    s[t] += x;
    __syncthreads();
  }
  if (t < B) bsum[t] = s[t] - v;
}

// Finalize rp and init per-bucket stage cursors (8-record-aligned bases).
__global__ void scan3_kernel(int* __restrict__ rp, const int* __restrict__ bsum,
                             int* __restrict__ bcur, int n, int nE) {
  int i = blockIdx.x * blockDim.x + threadIdx.x;
  if (i < n) {
    int v = rp[i] + bsum[i >> 10];
    rp[i] = v;
    if ((i & (BROWS - 1)) == 0)
      bcur[i >> BSH] = ((v >> 3) << 3) + ((i >> BSH) << 3);
  }
  if (i == 0) rp[n] = nE;
}

// Bucket bin: 64 blocks stream the edge list once; LDS-stage per bucket;
// flush aligned 64 B groups (4x int4) so every stage store is a full line.
// bs = batch size (edges per block-wide batch), tuned so per-bucket per-batch
// occupancy ~4 (overflow fallback prob ~1e-3 -> few hundred single appends).
__global__ void bin_kernel(const int* __restrict__ rows, const int* __restrict__ cols,
                           const uint32_t* __restrict__ pk,
                           int* __restrict__ bcur, int2* __restrict__ stage,
                           int nE, int nBkt, int bs) {
  __shared__ __align__(16) int2 buf[MAXBKT][BCAP];
  __shared__ int fill[MAXBKT];
  int tid = threadIdx.x;
  for (int b = tid; b < nBkt; b += BIN_THREADS) fill[b] = 0;
  __syncthreads();
  int per = (nE + (int)gridDim.x - 1) / (int)gridDim.x;
  int e0 = blockIdx.x * per;
  int e1 = e0 + per; if (e1 > nE) e1 = nE;
  for (int base = e0; base < e1; base += bs) {
    // Phase A: bin up to bs edges into LDS
    if (tid < bs) {
      int e = base + tid;
      if (e < e1) {
        int r = rows[e];
        int c = cols[e];
        uint32_t w = pk[e];
        int b = r >> BSH;
        int2 m = make_int2(c | ((r & (BROWS - 1)) << 18), (int)w);
        int t = atomicAdd(&fill[b], 1);
        if (t < BCAP) buf[b][t] = m;
        else stage[atomicAdd(&bcur[b], 1)] = m;   // rare overflow fallback
      }
    }
    __syncthreads();
    // Phase B: one thread per bucket flushes full 8-record (64 B) groups
    if (tid < nBkt) {
      int b = tid;
      int f = fill[b]; if (f > BCAP) f = BCAP;
      int ng = f >> 3;
      if (ng) {
        int pos = atomicAdd(&bcur[b], ng << 3);
        const int4* src = (const int4*)&buf[b][0];
        int4* dst = (int4*)(stage + pos);
        for (int g = 0; g < (ng << 2); ++g) dst[g] = src[g];
        int rem = f & 7;
        for (int j = 0; j < rem; ++j) buf[b][j] = buf[b][(ng << 3) + j];
        fill[b] = rem;
      }
    }
    __syncthreads();
  }
  // tail: flush remaining partial groups (bounded: <=7 records x nBkt x blocks)
  if (tid < nBkt) {
    int b = tid;
    int f = fill[b]; if (f > BCAP) f = BCAP;
    if (f) {
      int pos = atomicAdd(&bcur[b], f);
      for (int j = 0; j < f; ++j) stage[pos + j] = buf[b][j];
    }
  }
}

// Local sort: one block per bucket; sequential stage read, LDS row cursors,
// final rec writes confined to this bucket's contiguous CSR region.
__global__ void localsort_kernel(const int* __restrict__ rp, const int2* __restrict__ stage,
                                 int2* __restrict__ rec, int n) {
  __shared__ int cur[BROWS];
  int b = blockIdx.x;
  int r0 = b << BSH;
  int base = rp[r0];
  int rend = (b + 1) << BSH; if (rend > n) rend = n;
  int end = rp[rend];
  for (int j = threadIdx.x; j < BROWS; j += blockDim.x) {
    int r = r0 + j;
    cur[j] = (r < n) ? rp[r] : end;
  }
  __syncthreads();
  int sbase = ((base >> 3) << 3) + (b << 3);
  int cnt = end - base;
  for (int i = threadIdx.x; i < cnt; i += blockDim.x) {
    int2 m = stage[sbase + i];
    int rlo = (int)(((uint32_t)m.x) >> 18);
    int col = m.x & 0x3FFFF;
    int pos = atomicAdd(&cur[rlo], 1);
    rec[pos] = make_int2(col * DD, m.y);
  }
}

// ---------------------------------------------------------------------------
// Gather SpMM core, BATCHED BRANCH-FREE subgroup-per-row (R11): per 8-edge
// batch, load 8 recs, then issue all 8 feature loads with no intervening
// branches (dropped edges contribute exact 0*x), accumulate into 2
// interleaved accumulator sets. ~8 feature loads in flight per subgroup.
// ---------------------------------------------------------------------------
#define FMA8(c0, c1, v, q) { \
    c0.x += v * bflo(q.x); c0.y += v * bfhi(q.x); \
    c0.z += v * bflo(q.y); c0.w += v * bfhi(q.y); \
    c1.x += v * bflo(q.z); c1.y += v * bfhi(q.z); \
    c1.z += v * bflo(q.w); c1.w += v * bfhi(q.w); }

template <int VS>
__device__ __forceinline__ void gather_sub(int s0, int s1, const int2* __restrict__ rec,
                                           const ushort* __restrict__ src,
                                           int fl, float4& A0, float4& A1) {
  float4 a0 = make_float4(0.f, 0.f, 0.f, 0.f);
  float4 a1 = make_float4(0.f, 0.f, 0.f, 0.f);
  float4 b0 = make_float4(0.f, 0.f, 0.f, 0.f);
  float4 b1 = make_float4(0.f, 0.f, 0.f, 0.f);
  const ushort* sl = src + fl * 8;   // this lane's 16 B slice base
  int i = s0;
  for (; i + 8 <= s1; i += 8) {
    long long r[8];
    uint4 q[8];
#pragma unroll
    for (int u = 0; u < 8; ++u)
      r[u] = __builtin_nontemporal_load((const long long*)(rec + i + u));
#pragma unroll
    for (int u = 0; u < 8; ++u)
      q[u] = *(const uint4*)(sl + (uint32_t)r[u]);
#pragma unroll
    for (int u = 0; u < 8; ++u) {
      uint32_t w = (uint32_t)((unsigned long long)r[u] >> 32);
      float v = VS ? bfhi(w) : bflo(w);
      if (u & 1) { FMA8(b0, b1, v, q[u]) } else { FMA8(a0, a1, v, q[u]) }
    }
  }
  if (i + 4 <= s1) {
    long long r[4];
    uint4 q[4];
#pragma unroll
    for (int u = 0; u < 4; ++u)
      r[u] = __builtin_nontemporal_load((const long long*)(rec + i + u));
#pragma unroll
    for (int u = 0; u < 4; ++u)
      q[u] = *(const uint4*)(sl + (uint32_t)r[u]);
#pragma unroll
    for (int u = 0; u < 4; ++u) {
      uint32_t w = (uint32_t)((unsigned long long)r[u] >> 32);
      float v = VS ? bfhi(w) : bflo(w);
      if (u & 1) { FMA8(b0, b1, v, q[u]) } else { FMA8(a0, a1, v, q[u]) }
    }
    i += 4;
  }
  for (; i < s1; ++i) {
    long long rr = __builtin_nontemporal_load((const long long*)(rec + i));
    uint4 q = *(const uint4*)(sl + (uint32_t)rr);
    uint32_t w = (uint32_t)((unsigned long long)rr >> 32);
    float v = VS ? bfhi(w) : bflo(w);
    FMA8(a0, a1, v, q)
  }
  A0 = make_float4(a0.x + b0.x, a0.y + b0.y, a0.z + b0.z, a0.w + b0.w);
  A1 = make_float4(a1.x + b1.x, a1.y + b1.y, a1.z + b1.z, a1.w + b1.w);
}

__device__ __forceinline__ float4 lk4(float4 x) {
  x.x = x.x >= 0.0f ? x.x : 0.5f * x.x;
  x.y = x.y >= 0.0f ? x.y : 0.5f * x.y;
  x.z = x.z >= 0.0f ? x.z : 0.5f * x.z;
  x.w = x.w >= 0.0f ? x.w : 0.5f * x.w;
  return x;
}

__device__ __forceinline__ uint4 pack8(float4 a, float4 b) {
  uint4 p;
  p.x = f2bf(a.x) | (f2bf(a.y) << 16);
  p.y = f2bf(a.z) | (f2bf(a.w) << 16);
  p.z = f2bf(b.x) | (f2bf(b.y) << 16);
  p.w = f2bf(b.z) | (f2bf(b.w) << 16);
  return p;
}

// Mega gather; grid covers NN rows (+TAG_N virtual rows when WITHTAG).
// r < NN:  o = leaky(adj) + (r<USER ? leaky(soc) : leaky(tag item row))
//   FINAL=false: latOut(bf16) = o ; FINAL=true: acc(f32) += f32(lat[r]) + o
// r >= NN (WITHTAG only): rr = r-NN; tgOut[rr] = leaky(tag row ITEM_N+rr)
// Tag source region = lat + USER_N*DD is CONTIGUOUS [items][tags] by layout.
template <int VS, bool FINAL, bool WITHTAG>
__global__ void gather_mega_kernel(
    const int* __restrict__ arp, const int2* __restrict__ arec,
    const int* __restrict__ srp, const int2* __restrict__ srec,
    const int* __restrict__ trp, const int2* __restrict__ trec,
    const ushort* __restrict__ lat,   // NN x 64 bf16 (tag rows follow it)
    ushort* __restrict__ latOut, ushort* __restrict__ tgOut,
    float* __restrict__ acc) {
  int r = (blockIdx.x * blockDim.x + threadIdx.x) >> 3;
  int fl = threadIdx.x & 7;
  if (WITHTAG && r >= NN) {
    int rr = r - NN;
    if (rr >= TAG_N) return;
    int tr = rr + ITEM_N;
    float4 a0, a1;
    gather_sub<VS>(trp[tr], trp[tr + 1], trec, lat + (size_t)USER_N * DD, fl, a0, a1);
    ((uint4*)(tgOut + (size_t)rr * DD))[fl] = pack8(lk4(a0), lk4(a1));
    return;
  }
  if (r >= NN) return;
  float4 t0, t1, b0, b1;
  gather_sub<VS>(arp[r], arp[r + 1], arec, lat, fl, t0, t1);
  if (r < USER_N) {
    gather_sub<VS>(srp[r], srp[r + 1], srec, lat, fl, b0, b1);
  } else {
    int tr = r - USER_N;
    gather_sub<VS>(trp[tr], trp[tr + 1], trec, lat + (size_t)USER_N * DD, fl, b0, b1);
  }
  t0 = lk4(t0); t1 = lk4(t1); b0 = lk4(b0); b1 = lk4(b1);
  float4 o0 = make_float4(t0.x + b0.x, t0.y + b0.y, t0.z + b0.z, t0.w + b0.w);
  float4 o1 = make_float4(t1.x + b1.x, t1.y + b1.y, t1.z + b1.z, t1.w + b1.w);
  if (FINAL) {
    uint4 l = ((const uint4*)(lat + (size_t)r * DD))[fl];
    float4* ap = (float4*)(acc + (size_t)r * DD);
    float4 v0 = ap[fl * 2], v1 = ap[fl * 2 + 1];
    v0.x += bflo(l.x) + o0.x; v0.y += bfhi(l.x) + o0.y;
    v0.z += bflo(l.y) + o0.z; v0.w += bfhi(l.y) + o0.w;
    v1.x += bflo(l.z) + o1.x; v1.y += bfhi(l.z) + o1.y;
    v1.z += bflo(l.w) + o1.z; v1.w += bfhi(l.w) + o1.w;
    ap[fl * 2] = v0; ap[fl * 2 + 1] = v1;
  } else {
    ((uint4*)(latOut + (size_t)r * DD))[fl] = pack8(o0, o1);
  }
}

// acc(f32) = lat0 = concat(u, i); lat0bf = bf16(lat0); tEmbf = bf16(tEmbeds)
__global__ void init_kernel(const float4* __restrict__ u, const float4* __restrict__ it,
                            const float4* __restrict__ tE,
                            float4* __restrict__ acc, ushort4* __restrict__ lat0bf,
                            ushort4* __restrict__ tEmbf) {
  int idx = blockIdx.x * blockDim.x + threadIdx.x;  // NN*16 + TAG_N*16 float4s
  const int uN = USER_N * 16, nN = NN * 16;
  if (idx < nN) {
    float4 v = (idx < uN) ? u[idx] : it[idx - uN];
    acc[idx] = v;
    ushort4 h;
    h.x = (ushort)f2bf(v.x); h.y = (ushort)f2bf(v.y);
    h.z = (ushort)f2bf(v.z); h.w = (ushort)f2bf(v.w);
    lat0bf[idx] = h;
  } else if (idx < nN + TAG_N * 16) {
    int j = idx - nN;
    float4 v = tE[j];
    ushort4 h;
    h.x = (ushort)f2bf(v.x); h.y = (ushort)f2bf(v.y);
    h.z = (ushort)f2bf(v.z); h.w = (ushort)f2bf(v.w);
    tEmbf[j] = h;
  }
}

extern "C" void kernel_launch(void* const* d_in, const int* in_sizes, int n_in,
                              void* d_out, int out_size, void* d_ws, size_t ws_size,
                              hipStream_t stream) {
  const float* uE    = (const float*)d_in[0];
  const float* iE    = (const float*)d_in[1];
  const float* tEm   = (const float*)d_in[2];
  const int*   adj_r = (const int*)d_in[3];
  const int*   adj_c = (const int*)d_in[4];
  const float* adj_v = (const float*)d_in[5];
  const int*   tag_r = (const int*)d_in[6];
  const int*   tag_c = (const int*)d_in[7];
  const float* tag_v = (const float*)d_in[8];
  const int*   soc_r = (const int*)d_in[9];
  const int*   soc_c = (const int*)d_in[10];
  const float* soc_v = (const float*)d_in[11];
  const int nAdj = in_sizes[5], nTag = in_sizes[8], nSoc = in_sizes[11];

  float* acc = (float*)d_out;

  // Workspace (~86 MB). Layout makes BOTH tag-gather source regions
  // contiguous: [lat0 items][tEmbf] and [lat1 items][tg1bf].
  // During CSR build, lat1bf+tg1bf (21.76 MB) is dead -> reused as the
  // bucket STAGE buffer (needs nAdj+8*MAXBKT recs = 16.02 MB).
  ushort* lat0bf = (ushort*)d_ws;                  // NN*DD bf16
  ushort* tEmbf  = lat0bf + (size_t)NN * DD;       // TAG_N*DD (follows lat0!)
  ushort* lat1bf = tEmbf  + (size_t)TAG_N * DD;    // NN*DD
  ushort* tg1bf  = lat1bf + (size_t)NN * DD;       // TAG_N*DD (follows lat1!)
  int2* stage = (int2*)lat1bf;                     // CSR-build-phase alias
  int2* a_rec = (int2*)(tg1bf + (size_t)TAG_N * DD);  // nAdj {col*DD, bf16v0|bf16v1}
  int2* t_rec = a_rec + nAdj;                      // nTag
  int2* s_rec = t_rec + nTag;                      // nSoc
  int* ip    = (int*)(s_rec + nSoc);
  int* a_rp  = ip;  ip += NN + 1;
  int* a_cnt = ip;  ip += NN;
  int* t_rp  = ip;  ip += MM + 1;
  int* t_cnt = ip;  ip += MM;
  int* s_rp  = ip;  ip += USER_N + 1;
  int* s_cnt = ip;  ip += USER_N;
  int* bsum  = ip;  ip += 256;
  int* bcur  = ip;  ip += 512;                     // per-bucket stage cursors
  // shared packed-value side array (reused per graph, sequential builds)
  int nPkMax = nAdj > nTag ? nAdj : nTag;
  if (nSoc > nPkMax) nPkMax = nSoc;
  uint32_t* pkbuf = (uint32_t*)ip;  ip += nPkMax;

  // fold_in(key(42), j) for j=0..5 (host-side, deterministic)
  uint32_t kk[6][2];
  for (uint32_t j = 0; j < 6; ++j) tf2x32(0u, 42u, 0u, j, &kk[j][0], &kk[j][1]);

  const int thr = 256;
#define CDIV(a, b) (((a) + (b) - 1) / (b))

  // ---- CSR build (once per call; records carry both layers' values) ----
  struct G { const int* rows; const int* cols; const float* vals; int n; int nE;
             int* rp; int* cnt; int2* rec; int k0; int k1; };
  G gs[3] = {
      {adj_r, adj_c, adj_v, NN,     nAdj, a_rp, a_cnt, a_rec, 0, 3},
      {tag_r, tag_c, tag_v, MM,     nTag, t_rp, t_cnt, t_rec, 1, 4},
      {soc_r, soc_c, soc_v, USER_N, nSoc, s_rp, s_cnt, s_rec, 2, 5},
  };
  for (int g = 0; g < 3; ++g) {
    int n = gs[g].n, nE = gs[g].nE;
    int nBkt = CDIV(n, BROWS);
    int bs = 4 * nBkt; if (bs > BIN_THREADS) bs = BIN_THREADS; bs &= ~63;
    hipMemsetAsync(gs[g].cnt, 0, (size_t)n * sizeof(int), stream);
    histpack_kernel<<<CDIV(nE, thr), thr, 0, stream>>>(
        gs[g].rows, gs[g].vals, gs[g].cnt, pkbuf, nE,
        kk[gs[g].k0][0], kk[gs[g].k0][1], kk[gs[g].k1][0], kk[gs[g].k1][1]);
    int B = CDIV(n, 1024);
    scan1_kernel<<<B, 256, 0, stream>>>(gs[g].cnt, gs[g].rp, bsum, n);
    scan2_kernel<<<1, 256, 0, stream>>>(bsum, B);
    scan3_kernel<<<CDIV(n, thr), thr, 0, stream>>>(gs[g].rp, bsum, bcur, n, nE);
    bin_kernel<<<BIN_BLOCKS, BIN_THREADS, 0, stream>>>(
        gs[g].rows, gs[g].cols, pkbuf, bcur, stage, nE, nBkt, bs);
    localsort_kernel<<<nBkt, thr, 0, stream>>>(gs[g].rp, stage, gs[g].rec, n);
  }

  // ---- init: acc = lat0 (f32); lat0bf, tEmbf (bf16 gather sources) ----
  init_kernel<<<CDIV((NN + TAG_N) * 16, thr), thr, 0, stream>>>(
      (const float4*)uE, (const float4*)iE, (const float4*)tEm,
      (float4*)acc, (ushort4*)lat0bf, (ushort4*)tEmbf);

  // ---- layer 0 (tag-node rows fused into the same launch) ----
  // lat1 = combine(leaky(adj), leaky(soc) | leaky(tag item rows));
  // tg1 = leaky(tag-spmm tag rows) for layer-1 tag sources
  gather_mega_kernel<0, false, true><<<CDIV((NN + TAG_N) * 8, thr), thr, 0, stream>>>(
      a_rp, a_rec, s_rp, s_rec, t_rp, t_rec, lat0bf, lat1bf, tg1bf, nullptr);

  // ---- layer 1 ----
  // acc += lat1 + combine(leaky(adj), leaky(soc) | leaky(tag item rows))
  gather_mega_kernel<1, true, false><<<CDIV(NN * 8, thr), thr, 0, stream>>>(
      a_rp, a_rec, s_rp, s_rec, t_rp, t_rec, lat1bf, nullptr, nullptr, acc);
#undef CDIV
}

// Round 6
// 693.059 us; speedup vs baseline: 1.0779x; 1.0779x over previous
//
#include <hip/hip_runtime.h>
#include <stdint.h>

// Problem constants (match reference)
#define USER_N 100000
#define ITEM_N 50000
#define TAG_N  20000
#define NN (USER_N + ITEM_N)   // 150000 interaction-graph nodes
#define MM (ITEM_N + TAG_N)    // 70000 tag-graph nodes
#define DD 64
#define NT_ROWS (NN + MM + USER_N)   // 320000 merged rows (adj | tag | soc)

// Bucket scatter geometry (R13/R14)
#define BSH 9
#define BROWS (1 << BSH)       // 512 rows per bucket
#define NBKT0 293              // ceil(NN/512)          — round 0 (adj)
#define NBKT1 333              // ceil((MM+USER_N)/512) — round 1 (tag+soc)
#define BCAP 16                // LDS staged records per bucket
#define BIN_BLOCKS 128
#define BIN_THREADS 1024
#define BSLACK (8 * (BIN_BLOCKS + 2))  // per-bucket stage slack (pad budget + margin)
#define OCAP 32768             // overflow list capacity

// ---------------------------------------------------------------------------
// JAX threefry2x32 (20 rounds), bit-exact (verified: R1 absmax 0.0).
// ---------------------------------------------------------------------------
__host__ __device__ __forceinline__ void tf2x32(uint32_t k0, uint32_t k1,
                                                uint32_t x0, uint32_t x1,
                                                uint32_t* o0, uint32_t* o1) {
  uint32_t ks2 = k0 ^ k1 ^ 0x1BD11BDAu;
#define ROTL32(v, d) (((v) << (d)) | ((v) >> (32 - (d))))
#define TF_RND(d) { x0 += x1; x1 = ROTL32(x1, d); x1 ^= x0; }
  x0 += k0; x1 += k1;
  TF_RND(13) TF_RND(15) TF_RND(26) TF_RND(6)
  x0 += k1;  x1 += ks2 + 1u;
  TF_RND(17) TF_RND(29) TF_RND(16) TF_RND(24)
  x0 += ks2; x1 += k0 + 2u;
  TF_RND(13) TF_RND(15) TF_RND(26) TF_RND(6)
  x0 += k0;  x1 += k1 + 3u;
  TF_RND(17) TF_RND(29) TF_RND(16) TF_RND(24)
  x0 += k1;  x1 += ks2 + 4u;
  TF_RND(13) TF_RND(15) TF_RND(26) TF_RND(6)
  x0 += ks2; x1 += k0 + 5u;
  *o0 = x0; *o1 = x1;
#undef TF_RND
#undef ROTL32
}

// keep-mask(e; key), bit-exact vs jax uniform+floor (e = LOCAL per-graph idx)
__device__ __forceinline__ float drop_mask(uint32_t e, uint32_t k0, uint32_t k1) {
  uint32_t o0, o1;
  tf2x32(k0, k1, 0u, e, &o0, &o1);
  uint32_t bits = o0 ^ o1;
  float u = __uint_as_float((bits >> 9) | 0x3F800000u) - 1.0f;
  return floorf(u + 0.9f);
}

// bf16 helpers: RNE pack, exact shl unpack
__device__ __forceinline__ uint32_t f2bf(float f) {
  uint32_t u = __float_as_uint(f);
  return (u + 0x7fffu + ((u >> 16) & 1u)) >> 16;
}
__device__ __forceinline__ float bflo(uint32_t u) { return __uint_as_float(u << 16); }
__device__ __forceinline__ float bfhi(uint32_t u) { return __uint_as_float(u & 0xffff0000u); }

// ---------------------------------------------------------------------------
// MERGED CSR build (R13): ~10-13 us per DISPATCH overhead made 33 dispatches
// cost ~400 us of gaps. Merge all three graphs into one row space
// (adj 0..NN | tag NN..NN+MM | soc ..NT_ROWS): 1 memset + 1 histpack +
// 3 scans + 2x(bin+localsort) + init + 2 megas = 12 dispatches.
// bin/localsort carry R12's full-line invariant: a 64 B rec line is fully
// written within ONE block's short lifetime (bin: aligned 8-record group
// flushes; localsort: random writes confined to one bucket's ~55 KB region).
// R14 hardening: all stage writes bounds-checked vs stageCap; BSLACK has
// margin beyond the worst-case pad budget.
// ---------------------------------------------------------------------------

// One pass over ALL edges: histogram merged-row counts + threefry drop masks
// for both layers packed 2x bf16 into pk[e] (global e).
__global__ void histpack_kernel(const int* __restrict__ adj_r, const float* __restrict__ adj_v,
                                const int* __restrict__ tag_r, const float* __restrict__ tag_v,
                                const int* __restrict__ soc_r, const float* __restrict__ soc_v,
                                int* __restrict__ cnt, uint32_t* __restrict__ pk,
                                int nAdjE, int nTagE, int nSocE,
                                uint32_t a0, uint32_t a1, uint32_t a2, uint32_t a3,
                                uint32_t t0, uint32_t t1, uint32_t t2, uint32_t t3,
                                uint32_t s0, uint32_t s1, uint32_t s2, uint32_t s3) {
  int e = blockIdx.x * blockDim.x + threadIdx.x;
  int tot = nAdjE + nTagE + nSocE;
  if (e >= tot) return;
  int row, le; float v;
  uint32_t ka0, ka1, kb0, kb1;
  if (e < nAdjE) {
    le = e; row = adj_r[le]; v = adj_v[le];
    ka0 = a0; ka1 = a1; kb0 = a2; kb1 = a3;
  } else if (e < nAdjE + nTagE) {
    le = e - nAdjE; row = NN + tag_r[le]; v = tag_v[le];
    ka0 = t0; ka1 = t1; kb0 = t2; kb1 = t3;
  } else {
    le = e - nAdjE - nTagE; row = NN + MM + soc_r[le]; v = soc_v[le];
    ka0 = s0; ka1 = s1; kb0 = s2; kb1 = s3;
  }
  atomicAdd(&cnt[row], 1);
  const float SC = (float)(1.0 / 0.9);
  float v0 = v * drop_mask((uint32_t)le, ka0, ka1) * SC;
  float v1 = v * drop_mask((uint32_t)le, kb0, kb1) * SC;
  pk[e] = f2bf(v0) | (f2bf(v1) << 16);   // dropped -> exact 0 bits
}

__global__ void scan1_kernel(const int* __restrict__ cnt, int* __restrict__ rp,
                             int* __restrict__ bsum, int n) {
  __shared__ int s[256];
  int t = threadIdx.x;
  int base = blockIdx.x * 1024 + t * 4;
  int c0 = (base + 0 < n) ? cnt[base + 0] : 0;
  int c1 = (base + 1 < n) ? cnt[base + 1] : 0;
  int c2 = (base + 2 < n) ? cnt[base + 2] : 0;
  int c3 = (base + 3 < n) ? cnt[base + 3] : 0;
  int tsum = c0 + c1 + c2 + c3;
  s[t] = tsum;
  __syncthreads();
  for (int off = 1; off < 256; off <<= 1) {
    int v = (t >= off) ? s[t - off] : 0;
    __syncthreads();
    s[t] += v;
    __syncthreads();
  }
  int excl = s[t] - tsum;
  if (base + 0 < n) rp[base + 0] = excl;
  if (base + 1 < n) rp[base + 1] = excl + c0;
  if (base + 2 < n) rp[base + 2] = excl + c0 + c1;
  if (base + 3 < n) rp[base + 3] = excl + c0 + c1 + c2;
  if (t == 255) bsum[blockIdx.x] = s[255];
}

__global__ void scan2_kernel(int* __restrict__ bsum, int B) {
  __shared__ int s[512];
  int t = threadIdx.x;
  int v = (t < B) ? bsum[t] : 0;
  s[t] = v;
  __syncthreads();
  for (int off = 1; off < 512; off <<= 1) {
    int x = (t >= off) ? s[t - off] : 0;
    __syncthreads();
    s[t] += x;
    __syncthreads();
  }
  if (t < B) bsum[t] = s[t] - v;
}

// Finalize rp; init per-bucket stage cursors (8-aligned, BSLACK-spaced);
// zero overflow counters.
__global__ void scan3_kernel(int* __restrict__ rp, const int* __restrict__ bsum,
                             int* __restrict__ bcur, int* __restrict__ ocnt,
                             int nAdjE, int totE) {
  int i = blockIdx.x * blockDim.x + threadIdx.x;
  if (i < NT_ROWS) {
    int v = rp[i] + bsum[i >> 10];
    rp[i] = v;
    if (i < NN) {
      if ((i & (BROWS - 1)) == 0) {
        int lb = i >> BSH;
        bcur[lb] = ((v >> 3) << 3) + lb * BSLACK;
      }
    } else {
      int j = i - NN;
      if ((j & (BROWS - 1)) == 0) {
        int lb = j >> BSH;
        bcur[NBKT0 + lb] = (((v - nAdjE) >> 3) << 3) + lb * BSLACK;
      }
    }
  }
  if (i == 0) { rp[NT_ROWS] = totE; ocnt[0] = 0; ocnt[1] = 0; }
}

// Bucket bin (one round): stream a slice of the merged edge range once,
// LDS-stage per bucket, flush aligned 64 B 8-record groups. Tail flush pads
// with sentinel recs (x = -1) to keep every store a full line; overflow
// (LDS bucket full) goes to a separate list, never through the cursor.
// All stage writes bounds-checked vs stageCap (defensive; no-op normally).
__global__ __launch_bounds__(BIN_THREADS) void bin_kernel(
    const int* __restrict__ adj_r, const int* __restrict__ adj_c,
    const int* __restrict__ tag_r, const int* __restrict__ tag_c,
    const int* __restrict__ soc_r, const int* __restrict__ soc_c,
    const uint32_t* __restrict__ pk,
    int* __restrict__ bcur, int* __restrict__ ocnt,
    int2* __restrict__ ofl, int* __restrict__ obkt,
    int2* __restrict__ stage, int stageCap,
    int eBase, int eEnd, int nAdjE, int nTagE,
    int bktBase, int nBkt, int round) {
  __shared__ __align__(16) int2 buf[NBKT1][BCAP];
  __shared__ int fill[NBKT1];
  int tid = threadIdx.x;
  for (int b = tid; b < NBKT1; b += BIN_THREADS) fill[b] = 0;
  __syncthreads();
  int per = ((eEnd - eBase) + (int)gridDim.x - 1) / (int)gridDim.x;
  int e0 = eBase + blockIdx.x * per;
  int e1 = e0 + per; if (e1 > eEnd) e1 = eEnd;
  for (int base = e0; base < e1; base += BIN_THREADS) {
    int e = base + tid;
    if (e < e1) {
      int j, c;
      if (round == 0) {
        j = __builtin_nontemporal_load(&adj_r[e]);
        c = __builtin_nontemporal_load(&adj_c[e]);
      } else if (e < nAdjE + nTagE) {
        j = __builtin_nontemporal_load(&tag_r[e - nAdjE]);
        c = __builtin_nontemporal_load(&tag_c[e - nAdjE]);
      } else {
        j = MM + __builtin_nontemporal_load(&soc_r[e - nAdjE - nTagE]);
        c = __builtin_nontemporal_load(&soc_c[e - nAdjE - nTagE]);
      }
      uint32_t w = __builtin_nontemporal_load(&pk[e]);
      int lb = j >> BSH;
      int2 m = make_int2(c | ((j & (BROWS - 1)) << 18), (int)w);
      int t = atomicAdd(&fill[lb], 1);
      if (t < BCAP) buf[lb][t] = m;
      else {
        int oi = atomicAdd(ocnt, 1);
        if (oi < OCAP) { ofl[oi] = m; obkt[oi] = bktBase + lb; }
      }
    }
    __syncthreads();
    if (tid < nBkt) {
      int f = fill[tid]; if (f > BCAP) f = BCAP;
      int ng = f >> 3;
      if (ng) {
        int pos = atomicAdd(&bcur[bktBase + tid], ng << 3);
        if (pos + (ng << 3) <= stageCap) {
          int4* dst = (int4*)(stage + pos);
          const int4* src = (const int4*)&buf[tid][0];
          for (int g = 0; g < (ng << 2); ++g) dst[g] = src[g];
        }
        int rem = f & 7;
        for (int q = 0; q < rem; ++q) buf[tid][q] = buf[tid][(ng << 3) + q];
        fill[tid] = rem;
      }
    }
    __syncthreads();
  }
  // tail: pad to a full 64 B group with sentinels (localsort skips x<0)
  if (tid < nBkt) {
    int f = fill[tid]; if (f > BCAP) f = BCAP;
    if (f) {
      for (int q = f; q < 8; ++q) buf[tid][q] = make_int2(-1, 0);
      int pos = atomicAdd(&bcur[bktBase + tid], 8);
      if (pos + 8 <= stageCap) {
        int4* dst = (int4*)(stage + pos);
        const int4* src = (const int4*)&buf[tid][0];
        for (int g = 0; g < 4; ++g) dst[g] = src[g];
      }
    }
  }
}

// Local sort: one block per bucket; sequential stage read, LDS row cursors,
// final rec writes confined to this bucket's contiguous CSR region.
__global__ void localsort_kernel(const int* __restrict__ rp, const int* __restrict__ bcur,
                                 const int* __restrict__ ocnt,
                                 const int2* __restrict__ ofl, const int* __restrict__ obkt,
                                 const int2* __restrict__ stage, int2* __restrict__ rec,
                                 int rowStart, int rowEnd, int eBase, int bktBase) {
  __shared__ int cur[BROWS];
  int lb = blockIdx.x;
  int r0 = rowStart + (lb << BSH);
  int base = rp[r0];
  for (int jj = threadIdx.x; jj < BROWS; jj += blockDim.x) {
    int r = r0 + jj;
    cur[jj] = (r < rowEnd) ? rp[r] : rp[rowEnd];
  }
  __syncthreads();
  int sbase = (((base - eBase) >> 3) << 3) + lb * BSLACK;
  int nst = bcur[bktBase + lb] - sbase;
  for (int i = threadIdx.x; i < nst; i += blockDim.x) {
    long long rr = __builtin_nontemporal_load((const long long*)(stage + sbase + i));
    int mx = (int)(rr & 0xffffffffll);
    if (mx >= 0) {
      int rlo = ((uint32_t)mx) >> 18;
      int col = mx & 0x3FFFF;
      int pos = atomicAdd(&cur[rlo], 1);
      rec[pos] = make_int2(col * DD, (int)(rr >> 32));
    }
  }
  int oc = *ocnt; if (oc > OCAP) oc = OCAP;
  for (int i = threadIdx.x; i < oc; i += blockDim.x) {
    if (obkt[i] == bktBase + lb) {
      int2 m = ofl[i];
      int rlo = ((uint32_t)m.x) >> 18;
      int col = m.x & 0x3FFFF;
      int pos = atomicAdd(&cur[rlo], 1);
      rec[pos] = make_int2(col * DD, m.y);
    }
  }
}

// ---------------------------------------------------------------------------
// Gather SpMM core, BATCHED BRANCH-FREE subgroup-per-row (R11): per 8-edge
// batch, load 8 recs, then issue all 8 feature loads with no intervening
// branches (dropped edges contribute exact 0*x), accumulate into 2
// interleaved accumulator sets. ~8 feature loads in flight per subgroup.
// ---------------------------------------------------------------------------
#define FMA8(c0, c1, v, q) { \
    c0.x += v * bflo(q.x); c0.y += v * bfhi(q.x); \
    c0.z += v * bflo(q.y); c0.w += v * bfhi(q.y); \
    c1.x += v * bflo(q.z); c1.y += v * bfhi(q.z); \
    c1.z += v * bflo(q.w); c1.w += v * bfhi(q.w); }

template <int VS>
__device__ __forceinline__ void gather_sub(int s0, int s1, const int2* __restrict__ rec,
                                           const ushort* __restrict__ src,
                                           int fl, float4& A0, float4& A1) {
  float4 a0 = make_float4(0.f, 0.f, 0.f, 0.f);
  float4 a1 = make_float4(0.f, 0.f, 0.f, 0.f);
  float4 b0 = make_float4(0.f, 0.f, 0.f, 0.f);
  float4 b1 = make_float4(0.f, 0.f, 0.f, 0.f);
  const ushort* sl = src + fl * 8;   // this lane's 16 B slice base
  int i = s0;
  for (; i + 8 <= s1; i += 8) {
    long long r[8];
    uint4 q[8];
#pragma unroll
    for (int u = 0; u < 8; ++u)
      r[u] = __builtin_nontemporal_load((const long long*)(rec + i + u));
#pragma unroll
    for (int u = 0; u < 8; ++u)
      q[u] = *(const uint4*)(sl + (uint32_t)r[u]);
#pragma unroll
    for (int u = 0; u < 8; ++u) {
      uint32_t w = (uint32_t)((unsigned long long)r[u] >> 32);
      float v = VS ? bfhi(w) : bflo(w);
      if (u & 1) { FMA8(b0, b1, v, q[u]) } else { FMA8(a0, a1, v, q[u]) }
    }
  }
  if (i + 4 <= s1) {
    long long r[4];
    uint4 q[4];
#pragma unroll
    for (int u = 0; u < 4; ++u)
      r[u] = __builtin_nontemporal_load((const long long*)(rec + i + u));
#pragma unroll
    for (int u = 0; u < 4; ++u)
      q[u] = *(const uint4*)(sl + (uint32_t)r[u]);
#pragma unroll
    for (int u = 0; u < 4; ++u) {
      uint32_t w = (uint32_t)((unsigned long long)r[u] >> 32);
      float v = VS ? bfhi(w) : bflo(w);
      if (u & 1) { FMA8(b0, b1, v, q[u]) } else { FMA8(a0, a1, v, q[u]) }
    }
    i += 4;
  }
  for (; i < s1; ++i) {
    long long rr = __builtin_nontemporal_load((const long long*)(rec + i));
    uint4 q = *(const uint4*)(sl + (uint32_t)rr);
    uint32_t w = (uint32_t)((unsigned long long)rr >> 32);
    float v = VS ? bfhi(w) : bflo(w);
    FMA8(a0, a1, v, q)
  }
  A0 = make_float4(a0.x + b0.x, a0.y + b0.y, a0.z + b0.z, a0.w + b0.w);
  A1 = make_float4(a1.x + b1.x, a1.y + b1.y, a1.z + b1.z, a1.w + b1.w);
}

__device__ __forceinline__ float4 lk4(float4 x) {
  x.x = x.x >= 0.0f ? x.x : 0.5f * x.x;
  x.y = x.y >= 0.0f ? x.y : 0.5f * x.y;
  x.z = x.z >= 0.0f ? x.z : 0.5f * x.z;
  x.w = x.w >= 0.0f ? x.w : 0.5f * x.w;
  return x;
}

__device__ __forceinline__ uint4 pack8(float4 a, float4 b) {
  uint4 p;
  p.x = f2bf(a.x) | (f2bf(a.y) << 16);
  p.y = f2bf(a.z) | (f2bf(a.w) << 16);
  p.z = f2bf(b.x) | (f2bf(b.y) << 16);
  p.w = f2bf(b.z) | (f2bf(b.w) << 16);
  return p;
}

// Mega gather; grid covers NN rows (+TAG_N virtual rows when WITHTAG).
// r < NN:  o = leaky(adj) + (r<USER ? leaky(soc) : leaky(tag item row))
//   FINAL=false: latOut(bf16) = o ; FINAL=true: acc(f32) += f32(lat[r]) + o
// r >= NN (WITHTAG only): rr = r-NN; tgOut[rr] = leaky(tag row ITEM_N+rr)
// Tag source region = lat + USER_N*DD is CONTIGUOUS [items][tags] by layout.
template <int VS, bool FINAL, bool WITHTAG>
__global__ void gather_mega_kernel(
    const int* __restrict__ arp, const int2* __restrict__ arec,
    const int* __restrict__ srp, const int2* __restrict__ srec,
    const int* __restrict__ trp, const int2* __restrict__ trec,
    const ushort* __restrict__ lat,   // NN x 64 bf16 (tag rows follow it)
    ushort* __restrict__ latOut, ushort* __restrict__ tgOut,
    float* __restrict__ acc) {
  int r = (blockIdx.x * blockDim.x + threadIdx.x) >> 3;
  int fl = threadIdx.x & 7;
  if (WITHTAG && r >= NN) {
    int rr = r - NN;
    if (rr >= TAG_N) return;
    int tr = rr + ITEM_N;
    float4 a0, a1;
    gather_sub<VS>(trp[tr], trp[tr + 1], trec, lat + (size_t)USER_N * DD, fl, a0, a1);
    ((uint4*)(tgOut + (size_t)rr * DD))[fl] = pack8(lk4(a0), lk4(a1));
    return;
  }
  if (r >= NN) return;
  float4 t0, t1, b0, b1;
  gather_sub<VS>(arp[r], arp[r + 1], arec, lat, fl, t0, t1);
  if (r < USER_N) {
    gather_sub<VS>(srp[r], srp[r + 1], srec, lat, fl, b0, b1);
  } else {
    int tr = r - USER_N;
    gather_sub<VS>(trp[tr], trp[tr + 1], trec, lat + (size_t)USER_N * DD, fl, b0, b1);
  }
  t0 = lk4(t0); t1 = lk4(t1); b0 = lk4(b0); b1 = lk4(b1);
  float4 o0 = make_float4(t0.x + b0.x, t0.y + b0.y, t0.z + b0.z, t0.w + b0.w);
  float4 o1 = make_float4(t1.x + b1.x, t1.y + b1.y, t1.z + b1.z, t1.w + b1.w);
  if (FINAL) {
    uint4 l = ((const uint4*)(lat + (size_t)r * DD))[fl];
    float4* ap = (float4*)(acc + (size_t)r * DD);
    float4 v0 = ap[fl * 2], v1 = ap[fl * 2 + 1];
    v0.x += bflo(l.x) + o0.x; v0.y += bfhi(l.x) + o0.y;
    v0.z += bflo(l.y) + o0.z; v0.w += bfhi(l.y) + o0.w;
    v1.x += bflo(l.z) + o1.x; v1.y += bfhi(l.z) + o1.y;
    v1.z += bflo(l.w) + o1.z; v1.w += bfhi(l.w) + o1.w;
    ap[fl * 2] = v0; ap[fl * 2 + 1] = v1;
  } else {
    ((uint4*)(latOut + (size_t)r * DD))[fl] = pack8(o0, o1);
  }
}

// acc(f32) = lat0 = concat(u, i); lat0bf = bf16(lat0); tEmbf = bf16(tEmbeds)
__global__ void init_kernel(const float4* __restrict__ u, const float4* __restrict__ it,
                            const float4* __restrict__ tE,
                            float4* __restrict__ acc, ushort4* __restrict__ lat0bf,
                            ushort4* __restrict__ tEmbf) {
  int idx = blockIdx.x * blockDim.x + threadIdx.x;  // NN*16 + TAG_N*16 float4s
  const int uN = USER_N * 16, nN = NN * 16;
  if (idx < nN) {
    float4 v = (idx < uN) ? u[idx] : it[idx - uN];
    acc[idx] = v;
    ushort4 h;
    h.x = (ushort)f2bf(v.x); h.y = (ushort)f2bf(v.y);
    h.z = (ushort)f2bf(v.z); h.w = (ushort)f2bf(v.w);
    lat0bf[idx] = h;
  } else if (idx < nN + TAG_N * 16) {
    int j = idx - nN;
    float4 v = tE[j];
    ushort4 h;
    h.x = (ushort)f2bf(v.x); h.y = (ushort)f2bf(v.y);
    h.z = (ushort)f2bf(v.z); h.w = (ushort)f2bf(v.w);
    tEmbf[j] = h;
  }
}

extern "C" void kernel_launch(void* const* d_in, const int* in_sizes, int n_in,
                              void* d_out, int out_size, void* d_ws, size_t ws_size,
                              hipStream_t stream) {
  const float* uE    = (const float*)d_in[0];
  const float* iE    = (const float*)d_in[1];
  const float* tEm   = (const float*)d_in[2];
  const int*   adj_r = (const int*)d_in[3];
  const int*   adj_c = (const int*)d_in[4];
  const float* adj_v = (const float*)d_in[5];
  const int*   tag_r = (const int*)d_in[6];
  const int*   tag_c = (const int*)d_in[7];
  const float* tag_v = (const float*)d_in[8];
  const int*   soc_r = (const int*)d_in[9];
  const int*   soc_c = (const int*)d_in[10];
  const float* soc_v = (const float*)d_in[11];
  const int nAdj = in_sizes[5], nTag = in_sizes[8], nSoc = in_sizes[11];
  const int totE = nAdj + nTag + nSoc;

  float* acc = (float*)d_out;

  // Workspace (~79 MB). bf16 regions: [lat0 items][tEmbf] and [lat1][tg1bf]
  // contiguous (tag-gather single-base requirement). Build-phase aliases:
  // pk -> lat0bf region (16 MB <= 21.76), stage -> lat1bf region (<=19 MB).
  ushort* lat0bf = (ushort*)d_ws;                  // NN*DD bf16
  ushort* tEmbf  = lat0bf + (size_t)NN * DD;       // TAG_N*DD (follows lat0!)
  ushort* lat1bf = tEmbf  + (size_t)TAG_N * DD;    // NN*DD
  ushort* tg1bf  = lat1bf + (size_t)NN * DD;       // TAG_N*DD (follows lat1!)
  uint32_t* pk   = (uint32_t*)lat0bf;              // alias (dead until init)
  int2* stage    = (int2*)lat1bf;                  // alias (dead until mega0)
  const int stageCap = (int)(((size_t)(NN + TAG_N) * DD * 2) / sizeof(int2));
  int2* rec  = (int2*)(tg1bf + (size_t)TAG_N * DD);   // totE {col*DD, pk}
  int2* ofl  = rec + totE;                         // OCAP overflow recs
  int*  ip   = (int*)(ofl + OCAP);
  int* obkt  = ip;  ip += OCAP;
  int* rp    = ip;  ip += NT_ROWS + 1;
  int* cnt   = ip;  ip += NT_ROWS;
  int* bsum  = ip;  ip += 512;
  int* bcur  = ip;  ip += NBKT0 + NBKT1;
  int* ocnt  = ip;  ip += 2;

  // fold_in(key(42), j) for j=0..5 (host-side, deterministic)
  uint32_t kk[6][2];
  for (uint32_t j = 0; j < 6; ++j) tf2x32(0u, 42u, 0u, j, &kk[j][0], &kk[j][1]);

  const int thr = 256;
#define CDIV(a, b) (((a) + (b) - 1) / (b))

  // ---- merged CSR build: 9 dispatches total ----
  hipMemsetAsync(cnt, 0, (size_t)NT_ROWS * sizeof(int), stream);
  histpack_kernel<<<CDIV(totE, thr), thr, 0, stream>>>(
      adj_r, adj_v, tag_r, tag_v, soc_r, soc_v, cnt, pk, nAdj, nTag, nSoc,
      kk[0][0], kk[0][1], kk[3][0], kk[3][1],
      kk[1][0], kk[1][1], kk[4][0], kk[4][1],
      kk[2][0], kk[2][1], kk[5][0], kk[5][1]);
  int B = CDIV(NT_ROWS, 1024);
  scan1_kernel<<<B, 256, 0, stream>>>(cnt, rp, bsum, NT_ROWS);
  scan2_kernel<<<1, 512, 0, stream>>>(bsum, B);
  scan3_kernel<<<CDIV(NT_ROWS, thr), thr, 0, stream>>>(rp, bsum, bcur, ocnt, nAdj, totE);
  // round 0: adj rows [0, NN), edges [0, nAdj)
  bin_kernel<<<BIN_BLOCKS, BIN_THREADS, 0, stream>>>(
      adj_r, adj_c, tag_r, tag_c, soc_r, soc_c, pk, bcur, &ocnt[0], ofl, obkt,
      stage, stageCap, 0, nAdj, nAdj, nTag, 0, NBKT0, 0);
  localsort_kernel<<<NBKT0, thr, 0, stream>>>(
      rp, bcur, &ocnt[0], ofl, obkt, stage, rec, 0, NN, 0, 0);
  // round 1: tag+soc rows [NN, NT_ROWS), edges [nAdj, totE)
  bin_kernel<<<BIN_BLOCKS, BIN_THREADS, 0, stream>>>(
      adj_r, adj_c, tag_r, tag_c, soc_r, soc_c, pk, bcur, &ocnt[1], ofl, obkt,
      stage, stageCap, nAdj, totE, nAdj, nTag, NBKT0, NBKT1, 1);
  localsort_kernel<<<NBKT1, thr, 0, stream>>>(
      rp, bcur, &ocnt[1], ofl, obkt, stage, rec, NN, NT_ROWS, nAdj, NBKT0);

  // ---- init: acc = lat0 (f32); lat0bf, tEmbf (bf16 gather sources) ----
  init_kernel<<<CDIV((NN + TAG_N) * 16, thr), thr, 0, stream>>>(
      (const float4*)uE, (const float4*)iE, (const float4*)tEm,
      (float4*)acc, (ushort4*)lat0bf, (ushort4*)tEmbf);

  // ---- layer 0 (tag-node rows fused into the same launch) ----
  const int* arp = rp;
  const int* trp = rp + NN;
  const int* srp = rp + NN + MM;
  gather_mega_kernel<0, false, true><<<CDIV((NN + TAG_N) * 8, thr), thr, 0, stream>>>(
      arp, rec, srp, rec, trp, rec, lat0bf, lat1bf, tg1bf, nullptr);

  // ---- layer 1 ----
  gather_mega_kernel<1, true, false><<<CDIV(NN * 8, thr), thr, 0, stream>>>(
      arp, rec, srp, rec, trp, rec, lat1bf, nullptr, nullptr, acc);
#undef CDIV
}

// Round 7
// 552.262 us; speedup vs baseline: 1.3527x; 1.2549x over previous
//
#include <hip/hip_runtime.h>
#include <stdint.h>

// Problem constants (match reference)
#define USER_N 100000
#define ITEM_N 50000
#define TAG_N  20000
#define NN (USER_N + ITEM_N)   // 150000 interaction-graph nodes
#define MM (ITEM_N + TAG_N)    // 70000 tag-graph nodes
#define DD 64
#define NT_ROWS (NN + MM + USER_N)   // 320000 merged rows (adj | tag | soc)

// Bucket scatter geometry (R15)
#define BSH 9
#define BROWS (1 << BSH)       // 512 rows per bucket
#define NBKT0 293              // ceil(NN/512)          — round 0 (adj)
#define NBKT1 333              // ceil((MM+USER_N)/512) — round 1 (tag+soc)
#define BCAP 16                // LDS staged records per bucket
#define BIN_BLOCKS 128
#define BIN_THREADS 1024
#define OCAP 65536             // overflow list capacity

// ---------------------------------------------------------------------------
// JAX threefry2x32 (20 rounds), bit-exact (verified: R1 absmax 0.0).
// ---------------------------------------------------------------------------
__host__ __device__ __forceinline__ void tf2x32(uint32_t k0, uint32_t k1,
                                                uint32_t x0, uint32_t x1,
                                                uint32_t* o0, uint32_t* o1) {
  uint32_t ks2 = k0 ^ k1 ^ 0x1BD11BDAu;
#define ROTL32(v, d) (((v) << (d)) | ((v) >> (32 - (d))))
#define TF_RND(d) { x0 += x1; x1 = ROTL32(x1, d); x1 ^= x0; }
  x0 += k0; x1 += k1;
  TF_RND(13) TF_RND(15) TF_RND(26) TF_RND(6)
  x0 += k1;  x1 += ks2 + 1u;
  TF_RND(17) TF_RND(29) TF_RND(16) TF_RND(24)
  x0 += ks2; x1 += k0 + 2u;
  TF_RND(13) TF_RND(15) TF_RND(26) TF_RND(6)
  x0 += k0;  x1 += k1 + 3u;
  TF_RND(17) TF_RND(29) TF_RND(16) TF_RND(24)
  x0 += k1;  x1 += ks2 + 4u;
  TF_RND(13) TF_RND(15) TF_RND(26) TF_RND(6)
  x0 += ks2; x1 += k0 + 5u;
  *o0 = x0; *o1 = x1;
#undef TF_RND
#undef ROTL32
}

// keep-mask(e; key), bit-exact vs jax uniform+floor (e = LOCAL per-graph idx)
__device__ __forceinline__ float drop_mask(uint32_t e, uint32_t k0, uint32_t k1) {
  uint32_t o0, o1;
  tf2x32(k0, k1, 0u, e, &o0, &o1);
  uint32_t bits = o0 ^ o1;
  float u = __uint_as_float((bits >> 9) | 0x3F800000u) - 1.0f;
  return floorf(u + 0.9f);
}

// bf16 helpers: RNE pack, exact shl unpack
__device__ __forceinline__ uint32_t f2bf(float f) {
  uint32_t u = __float_as_uint(f);
  return (u + 0x7fffu + ((u >> 16) & 1u)) >> 16;
}
__device__ __forceinline__ float bflo(uint32_t u) { return __uint_as_float(u << 16); }
__device__ __forceinline__ float bfhi(uint32_t u) { return __uint_as_float(u & 0xffff0000u); }

// ---------------------------------------------------------------------------
// CSR build (R15): NO histogram pass. R14's histpack showed WRITE 140 MB for
// a 16 MB payload: each per-edge device-scope atomicAdd is a ~32 B coherent
// fabric write (4M edges x 32 B = 128 MB) at ~1 TB/s -> 160 us. R15:
//  - threefry fused INTO bin (pk array gone: -32 MB traffic, -1 kernel)
//  - per-bucket counts via LDS lcnt + ONE atomicAdd per bucket per block
//  - fixed-cap per-bucket stage regions (no rp-derived cursors -> no scans)
//  - localsort computes rp itself: LDS 512-row histogram + prefix scan of
//    its own bucket, bucket base = prefix over bcnt (<=333 ints/block)
// Pipeline: prep, bin0, ls0, bin1, ls1, init, mega0, mega1 = 8 dispatches.
// Full-line invariant kept: bin flushes aligned 64 B 8-record groups;
// overflow past a bucket's cap diverts to ofl and sentinel-fills the claim.
// ---------------------------------------------------------------------------

// prep: bucket stage cursors at fixed bases; zero counts; rp[NT_ROWS]=totE.
__global__ void prep_kernel(int* __restrict__ bcur, int* __restrict__ bcnt,
                            int* __restrict__ ocnt, int* __restrict__ rp,
                            int cap0, int cap1, int totE) {
  int t = threadIdx.x;
  if (t < NBKT0) bcur[t] = t * cap0;
  else if (t < NBKT0 + NBKT1) bcur[t] = (t - NBKT0) * cap1;
  if (t < NBKT0 + NBKT1) bcnt[t] = 0;
  if (t == 0) { ocnt[0] = 0; ocnt[1] = 0; rp[NT_ROWS] = totE; }
}

// Bucket bin with fused threefry. Edge index e is LOCAL to this round:
// primary graph (adj | tag) for e < nPrim, secondary (soc) after, with
// secondary rows offset by rowOff2 in this round's local row space.
__global__ __launch_bounds__(BIN_THREADS) void bin_kernel(
    const int* __restrict__ pr, const int* __restrict__ pc, const float* __restrict__ pv,
    const int* __restrict__ sr, const int* __restrict__ scc, const float* __restrict__ sv,
    int* __restrict__ bcur, int* __restrict__ bcnt, int* __restrict__ ocnt,
    int2* __restrict__ ofl, int* __restrict__ obkt,
    int2* __restrict__ stage, int cap,
    int nPrim, int nTot, int rowOff2, int bktBase, int nBkt,
    uint32_t pa0, uint32_t pa1, uint32_t pb0, uint32_t pb1,
    uint32_t sa0, uint32_t sa1, uint32_t sb0, uint32_t sb1) {
  __shared__ __align__(16) int2 buf[NBKT1][BCAP];
  __shared__ int fill[NBKT1];
  __shared__ int lcnt[NBKT1];
  int tid = threadIdx.x;
  for (int b = tid; b < NBKT1; b += BIN_THREADS) { fill[b] = 0; lcnt[b] = 0; }
  __syncthreads();
  int per = (nTot + (int)gridDim.x - 1) / (int)gridDim.x;
  int e0 = blockIdx.x * per;
  int e1 = e0 + per; if (e1 > nTot) e1 = nTot;
  const float SC = (float)(1.0 / 0.9);
  for (int base = e0; base < e1; base += BIN_THREADS) {
    int e = base + tid;
    if (e < e1) {
      int j, c; float v; uint32_t le, k00, k01, k10, k11;
      if (e < nPrim) {
        le = (uint32_t)e;
        j = __builtin_nontemporal_load(&pr[e]);
        c = __builtin_nontemporal_load(&pc[e]);
        v = __builtin_nontemporal_load(&pv[e]);
        k00 = pa0; k01 = pa1; k10 = pb0; k11 = pb1;
      } else {
        le = (uint32_t)(e - nPrim);
        j = rowOff2 + __builtin_nontemporal_load(&sr[e - nPrim]);
        c = __builtin_nontemporal_load(&scc[e - nPrim]);
        v = __builtin_nontemporal_load(&sv[e - nPrim]);
        k00 = sa0; k01 = sa1; k10 = sb0; k11 = sb1;
      }
      uint32_t w = f2bf(v * drop_mask(le, k00, k01) * SC) |
                   (f2bf(v * drop_mask(le, k10, k11) * SC) << 16);
      int lb = j >> BSH;
      atomicAdd(&lcnt[lb], 1);
      int2 m = make_int2(c | ((j & (BROWS - 1)) << 18), (int)w);
      int t = atomicAdd(&fill[lb], 1);
      if (t < BCAP) buf[lb][t] = m;
      else {
        int oi = atomicAdd(ocnt, 1);
        if (oi < OCAP) { ofl[oi] = m; obkt[oi] = bktBase + lb; }
      }
    }
    __syncthreads();
    if (tid < nBkt) {
      int f = fill[tid]; if (f > BCAP) f = BCAP;
      int ng = f >> 3;
      if (ng) {
        int n = ng << 3;
        int pos = atomicAdd(&bcur[bktBase + tid], n);
        int limit = (tid + 1) * cap;
        if (pos + n <= limit) {
          int4* dst = (int4*)(stage + pos);
          const int4* src = (const int4*)&buf[tid][0];
          for (int g = 0; g < (ng << 2); ++g) dst[g] = src[g];
        } else {
          for (int k = pos; k < limit; ++k) stage[k] = make_int2(-1, 0);
          for (int q = 0; q < n; ++q) {
            int oi = atomicAdd(ocnt, 1);
            if (oi < OCAP) { ofl[oi] = buf[tid][q]; obkt[oi] = bktBase + tid; }
          }
        }
        int rem = f & 7;
        for (int q = 0; q < rem; ++q) buf[tid][q] = buf[tid][n + q];
        fill[tid] = rem;
      }
    }
    __syncthreads();
  }
  // tail: pad to a full 64 B group with sentinels (skipped downstream)
  if (tid < nBkt) {
    int f = fill[tid]; if (f > BCAP) f = BCAP;
    if (f) {
      for (int q = f; q < 8; ++q) buf[tid][q] = make_int2(-1, 0);
      int pos = atomicAdd(&bcur[bktBase + tid], 8);
      int limit = (tid + 1) * cap;
      if (pos + 8 <= limit) {
        int4* dst = (int4*)(stage + pos);
        const int4* src = (const int4*)&buf[tid][0];
        for (int g = 0; g < 4; ++g) dst[g] = src[g];
      } else {
        for (int k = pos; k < limit; ++k) stage[k] = make_int2(-1, 0);
        for (int q = 0; q < f; ++q) {
          int oi = atomicAdd(ocnt, 1);
          if (oi < OCAP) { ofl[oi] = buf[tid][q]; obkt[oi] = bktBase + tid; }
        }
      }
    }
    // publish real count once per bucket per block
    if (lcnt[tid]) atomicAdd(&bcnt[bktBase + tid], lcnt[tid]);
  }
}

// Local sort: one block per bucket. Pass 1: histogram rows (LDS), prefix
// scan, write rp. Pass 2: place records at final CSR positions. All rec
// writes confined to this bucket's contiguous region (full-line coalesce).
__global__ void localsort_kernel(int* __restrict__ rp, const int* __restrict__ bcnt,
                                 const int* __restrict__ bcur, const int* __restrict__ ocnt,
                                 const int2* __restrict__ ofl, const int* __restrict__ obkt,
                                 const int2* __restrict__ stage, int2* __restrict__ rec,
                                 int rowStart, int rowEnd, int eBase, int bktBase, int cap) {
  __shared__ int cur[BROWS];
  __shared__ int red[256];
  int tid = threadIdx.x, lb = blockIdx.x;
  // bucket base = eBase + prefix(bcnt)
  int ps = 0;
  for (int b = tid; b < lb; b += 256) ps += bcnt[bktBase + b];
  red[tid] = ps;
  for (int off = 128; off > 0; off >>= 1) {
    __syncthreads();
    if (tid < off) red[tid] += red[tid + off];
  }
  __syncthreads();
  int base = eBase + red[0];
  cur[tid] = 0; cur[tid + 256] = 0;
  __syncthreads();
  int sbase = lb * cap;
  int send = bcur[bktBase + lb];
  int slim = sbase + cap; if (send > slim) send = slim;
  int nst = send - sbase;
  for (int i = tid; i < nst; i += 256) {
    int mx = stage[sbase + i].x;
    if (mx >= 0) atomicAdd(&cur[((uint32_t)mx) >> 18], 1);
  }
  int oc = *ocnt; if (oc > OCAP) oc = OCAP;
  for (int i = tid; i < oc; i += 256)
    if (obkt[i] == bktBase + lb) atomicAdd(&cur[((uint32_t)ofl[i].x) >> 18], 1);
  __syncthreads();
  // 512-element exclusive scan (pairs per thread)
  int c0 = cur[2 * tid], c1 = cur[2 * tid + 1];
  int pairs = c0 + c1;
  red[tid] = pairs;
  __syncthreads();
  for (int off = 1; off < 256; off <<= 1) {
    int v = (tid >= off) ? red[tid - off] : 0;
    __syncthreads();
    red[tid] += v;
    __syncthreads();
  }
  int excl = red[tid] - pairs;
  int r0 = rowStart + (lb << BSH);
  int r = r0 + 2 * tid;
  int p0 = base + excl, p1 = base + excl + c0;
  if (r < rowEnd) rp[r] = p0;
  if (r + 1 < rowEnd) rp[r + 1] = p1;
  __syncthreads();
  cur[2 * tid] = p0; cur[2 * tid + 1] = p1;
  __syncthreads();
  // pass 2: place
  for (int i = tid; i < nst; i += 256) {
    int2 m = stage[sbase + i];
    if (m.x >= 0) {
      int pos = atomicAdd(&cur[((uint32_t)m.x) >> 18], 1);
      rec[pos] = make_int2((m.x & 0x3FFFF) * DD, m.y);
    }
  }
  for (int i = tid; i < oc; i += 256) {
    if (obkt[i] == bktBase + lb) {
      int2 m = ofl[i];
      int pos = atomicAdd(&cur[((uint32_t)m.x) >> 18], 1);
      rec[pos] = make_int2((m.x & 0x3FFFF) * DD, m.y);
    }
  }
}

// ---------------------------------------------------------------------------
// Gather SpMM core, BATCHED BRANCH-FREE subgroup-per-row (R11): per 8-edge
// batch, load 8 recs, then issue all 8 feature loads with no intervening
// branches (dropped edges contribute exact 0*x), accumulate into 2
// interleaved accumulator sets. ~8 feature loads in flight per subgroup.
// ---------------------------------------------------------------------------
#define FMA8(c0, c1, v, q) { \
    c0.x += v * bflo(q.x); c0.y += v * bfhi(q.x); \
    c0.z += v * bflo(q.y); c0.w += v * bfhi(q.y); \
    c1.x += v * bflo(q.z); c1.y += v * bfhi(q.z); \
    c1.z += v * bflo(q.w); c1.w += v * bfhi(q.w); }

template <int VS>
__device__ __forceinline__ void gather_sub(int s0, int s1, const int2* __restrict__ rec,
                                           const ushort* __restrict__ src,
                                           int fl, float4& A0, float4& A1) {
  float4 a0 = make_float4(0.f, 0.f, 0.f, 0.f);
  float4 a1 = make_float4(0.f, 0.f, 0.f, 0.f);
  float4 b0 = make_float4(0.f, 0.f, 0.f, 0.f);
  float4 b1 = make_float4(0.f, 0.f, 0.f, 0.f);
  const ushort* sl = src + fl * 8;   // this lane's 16 B slice base
  int i = s0;
  for (; i + 8 <= s1; i += 8) {
    long long r[8];
    uint4 q[8];
#pragma unroll
    for (int u = 0; u < 8; ++u)
      r[u] = __builtin_nontemporal_load((const long long*)(rec + i + u));
#pragma unroll
    for (int u = 0; u < 8; ++u)
      q[u] = *(const uint4*)(sl + (uint32_t)r[u]);
#pragma unroll
    for (int u = 0; u < 8; ++u) {
      uint32_t w = (uint32_t)((unsigned long long)r[u] >> 32);
      float v = VS ? bfhi(w) : bflo(w);
      if (u & 1) { FMA8(b0, b1, v, q[u]) } else { FMA8(a0, a1, v, q[u]) }
    }
  }
  if (i + 4 <= s1) {
    long long r[4];
    uint4 q[4];
#pragma unroll
    for (int u = 0; u < 4; ++u)
      r[u] = __builtin_nontemporal_load((const long long*)(rec + i + u));
#pragma unroll
    for (int u = 0; u < 4; ++u)
      q[u] = *(const uint4*)(sl + (uint32_t)r[u]);
#pragma unroll
    for (int u = 0; u < 4; ++u) {
      uint32_t w = (uint32_t)((unsigned long long)r[u] >> 32);
      float v = VS ? bfhi(w) : bflo(w);
      if (u & 1) { FMA8(b0, b1, v, q[u]) } else { FMA8(a0, a1, v, q[u]) }
    }
    i += 4;
  }
  for (; i < s1; ++i) {
    long long rr = __builtin_nontemporal_load((const long long*)(rec + i));
    uint4 q = *(const uint4*)(sl + (uint32_t)rr);
    uint32_t w = (uint32_t)((unsigned long long)rr >> 32);
    float v = VS ? bfhi(w) : bflo(w);
    FMA8(a0, a1, v, q)
  }
  A0 = make_float4(a0.x + b0.x, a0.y + b0.y, a0.z + b0.z, a0.w + b0.w);
  A1 = make_float4(a1.x + b1.x, a1.y + b1.y, a1.z + b1.z, a1.w + b1.w);
}

__device__ __forceinline__ float4 lk4(float4 x) {
  x.x = x.x >= 0.0f ? x.x : 0.5f * x.x;
  x.y = x.y >= 0.0f ? x.y : 0.5f * x.y;
  x.z = x.z >= 0.0f ? x.z : 0.5f * x.z;
  x.w = x.w >= 0.0f ? x.w : 0.5f * x.w;
  return x;
}

__device__ __forceinline__ uint4 pack8(float4 a, float4 b) {
  uint4 p;
  p.x = f2bf(a.x) | (f2bf(a.y) << 16);
  p.y = f2bf(a.z) | (f2bf(a.w) << 16);
  p.z = f2bf(b.x) | (f2bf(b.y) << 16);
  p.w = f2bf(b.z) | (f2bf(b.w) << 16);
  return p;
}

// Mega gather; grid covers NN rows (+TAG_N virtual rows when WITHTAG).
// r < NN:  o = leaky(adj) + (r<USER ? leaky(soc) : leaky(tag item row))
//   FINAL=false: latOut(bf16) = o ; FINAL=true: acc(f32) += f32(lat[r]) + o
// r >= NN (WITHTAG only): rr = r-NN; tgOut[rr] = leaky(tag row ITEM_N+rr)
// Tag source region = lat + USER_N*DD is CONTIGUOUS [items][tags] by layout.
template <int VS, bool FINAL, bool WITHTAG>
__global__ void gather_mega_kernel(
    const int* __restrict__ arp, const int2* __restrict__ arec,
    const int* __restrict__ srp, const int2* __restrict__ srec,
    const int* __restrict__ trp, const int2* __restrict__ trec,
    const ushort* __restrict__ lat,   // NN x 64 bf16 (tag rows follow it)
    ushort* __restrict__ latOut, ushort* __restrict__ tgOut,
    float* __restrict__ acc) {
  int r = (blockIdx.x * blockDim.x + threadIdx.x) >> 3;
  int fl = threadIdx.x & 7;
  if (WITHTAG && r >= NN) {
    int rr = r - NN;
    if (rr >= TAG_N) return;
    int tr = rr + ITEM_N;
    float4 a0, a1;
    gather_sub<VS>(trp[tr], trp[tr + 1], trec, lat + (size_t)USER_N * DD, fl, a0, a1);
    ((uint4*)(tgOut + (size_t)rr * DD))[fl] = pack8(lk4(a0), lk4(a1));
    return;
  }
  if (r >= NN) return;
  float4 t0, t1, b0, b1;
  gather_sub<VS>(arp[r], arp[r + 1], arec, lat, fl, t0, t1);
  if (r < USER_N) {
    gather_sub<VS>(srp[r], srp[r + 1], srec, lat, fl, b0, b1);
  } else {
    int tr = r - USER_N;
    gather_sub<VS>(trp[tr], trp[tr + 1], trec, lat + (size_t)USER_N * DD, fl, b0, b1);
  }
  t0 = lk4(t0); t1 = lk4(t1); b0 = lk4(b0); b1 = lk4(b1);
  float4 o0 = make_float4(t0.x + b0.x, t0.y + b0.y, t0.z + b0.z, t0.w + b0.w);
  float4 o1 = make_float4(t1.x + b1.x, t1.y + b1.y, t1.z + b1.z, t1.w + b1.w);
  if (FINAL) {
    uint4 l = ((const uint4*)(lat + (size_t)r * DD))[fl];
    float4* ap = (float4*)(acc + (size_t)r * DD);
    float4 v0 = ap[fl * 2], v1 = ap[fl * 2 + 1];
    v0.x += bflo(l.x) + o0.x; v0.y += bfhi(l.x) + o0.y;
    v0.z += bflo(l.y) + o0.z; v0.w += bfhi(l.y) + o0.w;
    v1.x += bflo(l.z) + o1.x; v1.y += bfhi(l.z) + o1.y;
    v1.z += bflo(l.w) + o1.z; v1.w += bfhi(l.w) + o1.w;
    ap[fl * 2] = v0; ap[fl * 2 + 1] = v1;
  } else {
    ((uint4*)(latOut + (size_t)r * DD))[fl] = pack8(o0, o1);
  }
}

// acc(f32) = lat0 = concat(u, i); lat0bf = bf16(lat0); tEmbf = bf16(tEmbeds)
__global__ void init_kernel(const float4* __restrict__ u, const float4* __restrict__ it,
                            const float4* __restrict__ tE,
                            float4* __restrict__ acc, ushort4* __restrict__ lat0bf,
                            ushort4* __restrict__ tEmbf) {
  int idx = blockIdx.x * blockDim.x + threadIdx.x;  // NN*16 + TAG_N*16 float4s
  const int uN = USER_N * 16, nN = NN * 16;
  if (idx < nN) {
    float4 v = (idx < uN) ? u[idx] : it[idx - uN];
    acc[idx] = v;
    ushort4 h;
    h.x = (ushort)f2bf(v.x); h.y = (ushort)f2bf(v.y);
    h.z = (ushort)f2bf(v.z); h.w = (ushort)f2bf(v.w);
    lat0bf[idx] = h;
  } else if (idx < nN + TAG_N * 16) {
    int j = idx - nN;
    float4 v = tE[j];
    ushort4 h;
    h.x = (ushort)f2bf(v.x); h.y = (ushort)f2bf(v.y);
    h.z = (ushort)f2bf(v.z); h.w = (ushort)f2bf(v.w);
    tEmbf[j] = h;
  }
}

extern "C" void kernel_launch(void* const* d_in, const int* in_sizes, int n_in,
                              void* d_out, int out_size, void* d_ws, size_t ws_size,
                              hipStream_t stream) {
  const float* uE    = (const float*)d_in[0];
  const float* iE    = (const float*)d_in[1];
  const float* tEm   = (const float*)d_in[2];
  const int*   adj_r = (const int*)d_in[3];
  const int*   adj_c = (const int*)d_in[4];
  const float* adj_v = (const float*)d_in[5];
  const int*   tag_r = (const int*)d_in[6];
  const int*   tag_c = (const int*)d_in[7];
  const float* tag_v = (const float*)d_in[8];
  const int*   soc_r = (const int*)d_in[9];
  const int*   soc_c = (const int*)d_in[10];
  const float* soc_v = (const float*)d_in[11];
  const int nAdj = in_sizes[5], nTag = in_sizes[8], nSoc = in_sizes[11];
  const int totE = nAdj + nTag + nSoc;

  float* acc = (float*)d_out;

  // Workspace (~64 MB live). bf16 regions: [lat0 items][tEmbf] and
  // [lat1][tg1bf] contiguous (tag-gather single-base requirement).
  // Build-phase alias: stage -> lat1bf region (dead until mega0).
  ushort* lat0bf = (ushort*)d_ws;                  // NN*DD bf16
  ushort* tEmbf  = lat0bf + (size_t)NN * DD;       // TAG_N*DD (follows lat0!)
  ushort* lat1bf = tEmbf  + (size_t)TAG_N * DD;    // NN*DD
  ushort* tg1bf  = lat1bf + (size_t)NN * DD;       // TAG_N*DD (follows lat1!)
  int2* stage    = (int2*)lat1bf;                  // alias (dead until mega0)
  const int stageRecs = (int)(((size_t)(NN + TAG_N) * DD * sizeof(ushort)) / sizeof(int2));
  const int cap0 = (stageRecs / NBKT0) & ~7;       // 9280
  const int cap1 = (stageRecs / NBKT1) & ~7;       // 8168
  int2* rec  = (int2*)(tg1bf + (size_t)TAG_N * DD);   // totE {col*DD, pk}
  int2* ofl  = rec + totE;                         // OCAP overflow recs
  int*  ip   = (int*)(ofl + OCAP);
  int* obkt  = ip;  ip += OCAP;
  int* rp    = ip;  ip += NT_ROWS + 1;
  int* bcur  = ip;  ip += NBKT0 + NBKT1;
  int* bcnt  = ip;  ip += NBKT0 + NBKT1;
  int* ocnt  = ip;  ip += 2;

  // fold_in(key(42), j) for j=0..5 (host-side, deterministic)
  uint32_t kk[6][2];
  for (uint32_t j = 0; j < 6; ++j) tf2x32(0u, 42u, 0u, j, &kk[j][0], &kk[j][1]);

  const int thr = 256;
#define CDIV(a, b) (((a) + (b) - 1) / (b))

  // ---- CSR build: prep + 2x(bin + localsort) = 5 dispatches ----
  prep_kernel<<<1, 1024, 0, stream>>>(bcur, bcnt, ocnt, rp, cap0, cap1, totE);
  // round 0: adj rows -> local rows [0, NN), edges [0, nAdj)
  bin_kernel<<<BIN_BLOCKS, BIN_THREADS, 0, stream>>>(
      adj_r, adj_c, adj_v, adj_r, adj_c, adj_v,   // secondary unused
      bcur, bcnt, &ocnt[0], ofl, obkt, stage, cap0,
      nAdj, nAdj, 0, 0, NBKT0,
      kk[0][0], kk[0][1], kk[3][0], kk[3][1], 0u, 0u, 0u, 0u);
  localsort_kernel<<<NBKT0, 256, 0, stream>>>(
      rp, bcnt, bcur, &ocnt[0], ofl, obkt, stage, rec, 0, NN, 0, 0, cap0);
  // round 1: tag (local rows [0,MM)) + soc (local rows [MM, MM+USER_N))
  bin_kernel<<<BIN_BLOCKS, BIN_THREADS, 0, stream>>>(
      tag_r, tag_c, tag_v, soc_r, soc_c, soc_v,
      bcur, bcnt, &ocnt[1], ofl, obkt, stage, cap1,
      nTag, nTag + nSoc, MM, NBKT0, NBKT1,
      kk[1][0], kk[1][1], kk[4][0], kk[4][1],
      kk[2][0], kk[2][1], kk[5][0], kk[5][1]);
  localsort_kernel<<<NBKT1, 256, 0, stream>>>(
      rp, bcnt, bcur, &ocnt[1], ofl, obkt, stage, rec, NN, NT_ROWS, nAdj, NBKT0, cap1);

  // ---- init: acc = lat0 (f32); lat0bf, tEmbf (bf16 gather sources) ----
  init_kernel<<<CDIV((NN + TAG_N) * 16, thr), thr, 0, stream>>>(
      (const float4*)uE, (const float4*)iE, (const float4*)tEm,
      (float4*)acc, (ushort4*)lat0bf, (ushort4*)tEmbf);

  // ---- layer 0 (tag-node rows fused into the same launch) ----
  const int* arp = rp;
  const int* trp = rp + NN;
  const int* srp = rp + NN + MM;
  gather_mega_kernel<0, false, true><<<CDIV((NN + TAG_N) * 8, thr), thr, 0, stream>>>(
      arp, rec, srp, rec, trp, rec, lat0bf, lat1bf, tg1bf, nullptr);

  // ---- layer 1 ----
  gather_mega_kernel<1, true, false><<<CDIV(NN * 8, thr), thr, 0, stream>>>(
      arp, rec, srp, rec, trp, rec, lat1bf, nullptr, nullptr, acc);
#undef CDIV
}